// Round 1
// baseline (50.481 us; speedup 1.0000x reference)
//
#include <hip/hip_runtime.h>
#include <hip/hip_bf16.h>

// RegionEmbeddingLayer: out[b,l,d] = max_{r<7}( word_emb[ids[b,l+r]][d] * ctx_emb[ids[b,l+3]][r*128+d] )
// B=32, S=2048, L=2042, D=128, REGION=7

#define RE_B 32
#define RE_S 2048
#define RE_RAD 3
#define RE_L (RE_S - 2 * RE_RAD)   // 2042
#define RE_D 128
#define RE_R 7
#define RE_DQ (RE_D / 4)           // 32 float4 per row

__global__ __launch_bounds__(256) void region_embed_kernel(
    const int* __restrict__ ids,        // [B, S]
    const float4* __restrict__ we,      // [V, 32]  (word_emb as float4)
    const float4* __restrict__ ce,      // [V, 7*32] (ctx_emb as float4)
    float4* __restrict__ out)           // [B*L, 32]
{
    const int total = RE_B * RE_L * RE_DQ;
    int idx = blockIdx.x * blockDim.x + threadIdx.x;
    if (idx >= total) return;

    int lane = idx & (RE_DQ - 1);       // which float4 within the 128-dim row
    int pos  = idx >> 5;                // (b, l) flattened
    int b = pos / RE_L;
    int l = pos - b * RE_L;

    const int* row = ids + b * RE_S + l;
    int t = row[RE_RAD];

    const float4* cbase = ce + (size_t)t * (RE_R * RE_DQ) + lane;

    float4 acc;
    acc.x = -INFINITY; acc.y = -INFINITY; acc.z = -INFINITY; acc.w = -INFINITY;

#pragma unroll
    for (int r = 0; r < RE_R; ++r) {
        int w = row[r];
        float4 ve = we[(size_t)w * RE_DQ + lane];
        float4 c  = cbase[r * RE_DQ];
        acc.x = fmaxf(acc.x, ve.x * c.x);
        acc.y = fmaxf(acc.y, ve.y * c.y);
        acc.z = fmaxf(acc.z, ve.z * c.z);
        acc.w = fmaxf(acc.w, ve.w * c.w);
    }

    out[(size_t)pos * RE_DQ + lane] = acc;
}

extern "C" void kernel_launch(void* const* d_in, const int* in_sizes, int n_in,
                              void* d_out, int out_size, void* d_ws, size_t ws_size,
                              hipStream_t stream) {
    const int*    ids = (const int*)d_in[0];
    const float4* we  = (const float4*)d_in[1];
    const float4* ce  = (const float4*)d_in[2];
    float4* out = (float4*)d_out;

    const int total = RE_B * RE_L * RE_DQ;   // 2,091,008 threads
    const int block = 256;
    const int grid = (total + block - 1) / block;
    region_embed_kernel<<<grid, block, 0, stream>>>(ids, we, ce, out);
}